// Round 10
// baseline (418.368 us; speedup 1.0000x reference)
//
#include <hip/hip_runtime.h>
#include <math.h>

#define DIM 384
#define NUM_HEADS 8
#define RES 14
#define RES2 7
#define NPOS 196
#define N2 49
#define DHEAD 64
#define NH_KD 128
#define DH 512
#define OUT_DIM 768
#define BATCH 512
#define SCALE_Q 0.25f

typedef unsigned short u16;
typedef short s16x8 __attribute__((ext_vector_type(8)));
typedef short s16x4 __attribute__((ext_vector_type(4)));
typedef float f32x4 __attribute__((ext_vector_type(4)));
typedef unsigned int u32x2 __attribute__((ext_vector_type(2)));

__device__ __forceinline__ float bf2f(u16 u) {
  union { unsigned int i; float f; } v; v.i = ((unsigned int)u) << 16; return v.f;
}
__device__ __forceinline__ u16 f2bf(float f) {
  union { unsigned int i; float f; } v; v.f = f;
  unsigned int r = v.i + 0x7fffu + ((v.i >> 16) & 1u);
  return (u16)(r >> 16);
}

#define GLD16(gp, lp) __builtin_amdgcn_global_load_lds( \
    (const __attribute__((address_space(1))) void*)(gp), \
    (__attribute__((address_space(3))) void*)(lp), 16, 0, 0)

// ---------- fused prep: concat kv-weights, weight casts, bias gather, param concat ----------
__global__ __launch_bounds__(256) void k_prep(const float* __restrict__ kw, const float* __restrict__ vw,
                                              const float* __restrict__ qw, const float* __restrict__ pw,
                                              const float* __restrict__ ab, const int* __restrict__ idxs, int noff,
                                              const float* __restrict__ kb, const float* __restrict__ kbs, const float* __restrict__ kbt,
                                              const float* __restrict__ vb, const float* __restrict__ vbs, const float* __restrict__ vbt,
                                              u16* __restrict__ wb, u16* __restrict__ qwb, u16* __restrict__ pwb,
                                              float* __restrict__ bxp,
                                              float* __restrict__ cvb, float* __restrict__ cvs, float* __restrict__ cvt) {
  int i = blockIdx.x * 256 + threadIdx.x;
  const int E1 = 640 * DIM;                  // 245760  wb = [vw(512); kw(128)]
  const int E2 = E1 + NH_KD * DIM;           // 294912  qwb
  const int E3 = E2 + OUT_DIM * DH;          // 688128  pwb
  const int E4 = E3 + NUM_HEADS * N2 * 256;  // 888832  bxp
  const int E5 = E4 + 3 * 640;               // 890752  concat params
  if (i < E1) wb[i] = f2bf(i < DH * DIM ? vw[i] : kw[i - DH * DIM]);
  else if (i < E2) qwb[i - E1] = f2bf(qw[i - E1]);
  else if (i < E3) pwb[i - E2] = f2bf(pw[i - E2]);
  else if (i < E4) {
    int j = i - E3;
    int f = j & 15, c = (j >> 4) & 15;
    int m = (j >> 8) % N2, h = j / (N2 * 256);
    int n = f * 16 + c;
    bxp[j] = (n < NPOS) ? ab[h * noff + idxs[m * NPOS + n]] : 0.f;
  } else if (i < E5) {
    int j = i - E4; int c = j % 640, t = j / 640;
    float v = (c < DH) ? (t == 0 ? vb[c] : t == 1 ? vbs[c] : vbt[c])
                       : (t == 0 ? kb[c - DH] : t == 1 ? kbs[c - DH] : kbt[c - DH]);
    (t == 0 ? cvb : t == 1 ? cvs : cvt)[c] = v;
  }
}

// ---------- x (f32 [b][384][196]) -> xbT (bf16 [b][196][384]) ----------
__global__ __launch_bounds__(256) void k_transpose(const float* __restrict__ x, u16* __restrict__ xt) {
  int b = blockIdx.y, c0 = blockIdx.x * 64;
  __shared__ u16 tile[64][196];
  int tid = threadIdx.x, wave = tid >> 6, lane = tid & 63;
  const float* xb = x + (size_t)b * DIM * NPOS;
  for (int r = wave; r < 64; r += 4) {
    const float* row = xb + (size_t)(c0 + r) * NPOS;
    tile[r][lane]       = f2bf(row[lane]);
    tile[r][lane + 64]  = f2bf(row[lane + 64]);
    tile[r][lane + 128] = f2bf(row[lane + 128]);
    if (lane < 4) tile[r][lane + 192] = f2bf(row[lane + 192]);
  }
  __syncthreads();
  u16* xtb = xt + (size_t)b * NPOS * DIM;
  for (int n = wave; n < NPOS; n += 4)
    xtb[(size_t)n * DIM + c0 + lane] = tile[lane][n];
}

// ---------- ql = dwconv_s2(x) + b + x[::2,::2] -> qlT, 8 channels/thread (G13) ----------
__global__ __launch_bounds__(256) void k_dwconv_q8(const u16* __restrict__ xt, const float* __restrict__ w,
                                                   const float* __restrict__ bias, u16* __restrict__ qlt) {
  int b = blockIdx.y;
  int lid = blockIdx.x * 256 + threadIdx.x;
  if (lid >= N2 * (DIM / 8)) return;
  int n2 = lid / (DIM / 8), c0 = (lid % (DIM / 8)) * 8;
  int r = n2 / RES2, s = n2 % RES2;
  const u16* xb = xt + (size_t)b * NPOS * DIM + c0;

  s16x8 xv[9];
#pragma unroll
  for (int dy = 0; dy < 3; dy++) {
    int ry = 2 * r - 1 + dy;
#pragma unroll
    for (int dx = 0; dx < 3; dx++) {
      int sx = 2 * s - 1 + dx;
      if (ry >= 0 && ry < RES && sx >= 0 && sx < RES)
        xv[dy * 3 + dx] = *(const s16x8*)(xb + (size_t)(ry * RES + sx) * DIM);
      else
        xv[dy * 3 + dx] = (s16x8){0, 0, 0, 0, 0, 0, 0, 0};
    }
  }
  s16x8 resid = *(const s16x8*)(xb + (size_t)(2 * r * RES + 2 * s) * DIM);
  s16x8 o;
#pragma unroll
  for (int e = 0; e < 8; e++) {
    const float* we = w + (size_t)(c0 + e) * 9;
    float a = bias[c0 + e] + bf2f((u16)resid[e]);
#pragma unroll
    for (int t = 0; t < 9; t++) a += we[t] * bf2f((u16)xv[t][e]);
    o[e] = (short)f2bf(a);
  }
  *(s16x8*)(qlt + ((size_t)b * N2 + n2) * DIM + c0) = o;
}

// ---------- flattened GEMM: C = A[M][K] x B[N][K]^T, both K-contiguous bf16 ----------
// 128x128 tile, BK=64 (two 8KB 32-K halves per operand, one barrier per 64-K).
// chunk = 1KB = 16 rows x 64B; wave w stages chunks w*2, w*2+1 via global_load_lds(16B).
// Source pre-swizzle (m173/rule21): lane fetches global granule (l&3)^((l>>3)&3);
// frag reads un-swizzle with rg8 = ((l>>4)^((l>>1)&3))*8 -> conflict-free both sides.
// SPLN=0: out[m*ldc + n] (ch=n). SPLN>0: out[(n/SPLN)*bstride + m*SPLN + n%SPLN] (ch=m).
// KMERGE: m-tiles >=512 are the k-projection -> C2[n*128 + (m-512)] (ch=m, concat params).
template <int SPLN, bool F32OUT, bool KMERGE>
__global__ __launch_bounds__(256) void k_gemm_flat(
    const u16* __restrict__ A, const u16* __restrict__ B, void* __restrict__ C, void* __restrict__ C2,
    const float* __restrict__ cb, const float* __restrict__ bns, const float* __restrict__ bnt,
    int K, int NMT, int ldc, long bstride) {
  __shared__ __align__(16) u16 a_lds[2 * 128 * 32];
  __shared__ __align__(16) u16 b_lds[2 * 128 * 32];
  int nwg = gridDim.x, bx = blockIdx.x;
  int wg = ((nwg & 7) == 0) ? ((bx & 7) * (nwg >> 3) + (bx >> 3)) : bx;  // XCD-bijective
  int mt = wg % NMT, nt = wg / NMT;                                      // m fastest: j-tile shared on-XCD
  int m0 = mt * 128, n0 = nt * 128;
  int tid = threadIdx.x, w = tid >> 6, l = tid & 63;

  int srow = l >> 2;
  int scol = ((l & 3) ^ ((l >> 3) & 3)) * 8;   // pre-swizzled source granule
  const u16* asrc[2]; const u16* bsrc[2];
#pragma unroll
  for (int c = 0; c < 2; c++) {
    int chunk = w * 2 + c;
    asrc[c] = A + (size_t)(m0 + chunk * 16 + srow) * K + scol;
    bsrc[c] = B + (size_t)(n0 + chunk * 16 + srow) * K + scol;
  }
  char* adst = (char*)a_lds + (w * 2) * 1024 + l * 16;
  char* bdst = (char*)b_lds + (w * 2) * 1024 + l * 16;

  f32x4 acc[4][4];
#pragma unroll
  for (int i = 0; i < 4; i++)
#pragma unroll
    for (int j = 0; j < 4; j++) acc[i][j] = (f32x4){0.f, 0.f, 0.f, 0.f};

  int wm = w >> 1, wn = w & 1;
  int rg8 = ((l >> 4) ^ ((l >> 1) & 3)) * 8;   // un-swizzling read granule
  int arow = wm * 64 + (l & 15);
  int brow = wn * 64 + (l & 15);

  for (int kk = 0; kk < K; kk += 64) {
#pragma unroll
    for (int c = 0; c < 2; c++) {
      GLD16(asrc[c] + kk,      adst + c * 1024);
      GLD16(asrc[c] + kk + 32, adst + 8192 + c * 1024);
      GLD16(bsrc[c] + kk,      bdst + c * 1024);
      GLD16(bsrc[c] + kk + 32, bdst + 8192 + c * 1024);
    }
    __syncthreads();                 // compiler drains vmcnt before barrier
#pragma unroll
    for (int hf = 0; hf < 2; hf++) {
      const u16* ah = a_lds + hf * (128 * 32);
      const u16* bh = b_lds + hf * (128 * 32);
      s16x8 af[4], bf[4];
#pragma unroll
      for (int i = 0; i < 4; i++) {
        af[i] = *(const s16x8*)(&ah[(arow + i * 16) * 32 + rg8]);
        bf[i] = *(const s16x8*)(&bh[(brow + i * 16) * 32 + rg8]);
      }
#pragma unroll
      for (int i = 0; i < 4; i++)
#pragma unroll
        for (int j = 0; j < 4; j++)
          acc[i][j] = __builtin_amdgcn_mfma_f32_16x16x32_bf16(af[i], bf[j], acc[i][j], 0, 0, 0);
    }
    __syncthreads();
  }

  int ncol = l & 15, mq = (l >> 4) * 4;
#pragma unroll
  for (int i = 0; i < 4; i++) {
#pragma unroll
    for (int j = 0; j < 4; j++) {
      int n = n0 + wn * 64 + j * 16 + ncol;
#pragma unroll
      for (int r = 0; r < 4; r++) {
        int m = m0 + wm * 64 + i * 16 + mq + r;
        int ch = (SPLN || KMERGE) ? m : n;
        float val = acc[i][j][r] * bns[ch] + (cb[ch] * bns[ch] + bnt[ch]);
        if (KMERGE && m0 >= DH) {          // block-uniform: k-projection tile
          ((u16*)C2)[(size_t)n * NH_KD + (m - DH)] = f2bf(val);
        } else {
          size_t o;
          if (SPLN) o = (size_t)(n / SPLN) * bstride + (size_t)m * SPLN + (n % SPLN);
          else      o = (size_t)m * ldc + n;
          if (F32OUT) ((float*)C)[o] = val;
          else        ((u16*)C)[o] = f2bf(val);
        }
      }
    }
  }
}

// ---------- v_local = BN(dwconv_s2(v4) + b) -> vlT (bf16 [b][49][512]) ----------
__global__ __launch_bounds__(256) void k_dwconv_v(const u16* __restrict__ v4, const float* __restrict__ w,
    const float* __restrict__ bias, const float* __restrict__ bns, const float* __restrict__ bnt,
    u16* __restrict__ vlt) {
  int b = blockIdx.y, ct = blockIdx.x;
  __shared__ u16 tile[64][196];
  int tid = threadIdx.x, wave = tid >> 6, lane = tid & 63;
  const u16* vbp = v4 + ((size_t)b * DH + ct * 64) * NPOS;
  for (int r = wave; r < 64; r += 4) {
    const u16* row = vbp + (size_t)r * NPOS;
    tile[r][lane]       = row[lane];
    tile[r][lane + 64]  = row[lane + 64];
    tile[r][lane + 128] = row[lane + 128];
    if (lane < 4) tile[r][lane + 192] = row[lane + 192];
  }
  __syncthreads();
  for (int idx = tid; idx < 64 * N2; idx += 256) {
    int cl = idx & 63, n2 = idx >> 6;
    int ch = ct * 64 + cl;
    int r = n2 / RES2, s = n2 % RES2;
    float acc = bias[ch];
#pragma unroll
    for (int dy = 0; dy < 3; dy++) {
      int ry = 2 * r - 1 + dy;
      if (ry < 0 || ry >= RES) continue;
#pragma unroll
      for (int dx = 0; dx < 3; dx++) {
        int sx = 2 * s - 1 + dx;
        if (sx < 0 || sx >= RES) continue;
        acc += w[ch * 9 + dy * 3 + dx] * bf2f(tile[cl][ry * RES + sx]);
      }
    }
    vlt[((size_t)b * N2 + n2) * DH + ch] = f2bf(acc * bns[ch] + bnt[ch]);
  }
}

// ---------- MFMA attention per (b,h), LDS = p_lds only (29.7 KB -> 4 blocks/CU @128 VGPR) ----------
// Q and K fragments read DIRECTLY from global (16B-aligned frag slices; part>=2 lanes = 0 for
// the K 16->32 pad; rows >=49/>=196 read in-ws garbage, masked to -1e30 before softmax).
// V read directly from v4 ([b][512][196] = B-operand rows) as 2x8B (r8-verified).
// o_lds overlaps p_lds: barrier after PV before o-write, barrier before epilogue.
__global__ __launch_bounds__(256, 4) void k_attn_mfma(const u16* __restrict__ qT, const u16* __restrict__ kT,
    const u16* __restrict__ v4, const float* __restrict__ bxp, const u16* __restrict__ vlT,
    u16* __restrict__ gT) {
  int h = blockIdx.x, b = blockIdx.y;
  __shared__ __align__(16) u16 p_lds[64 * 232];   // 29,696 B
  float* o_lds = (float*)p_lds;                   // overlap (barrier-protected)
  int tid = threadIdx.x, w = tid >> 6, l = tid & 63;
  int part = l >> 4, row16 = l & 15;
  int mbase = w * 16 + part * 4;
  int ncol = l & 15;

  // --- zero p_lds pad cols 208..223 (dwords 104..111) ---
  for (int idx = tid; idx < 64 * 8; idx += 256)
    ((uint*)&p_lds[(idx >> 3) * 232])[104 + (idx & 7)] = 0;

  // --- Q fragment direct from global ---
  s16x8 af = (s16x8){0, 0, 0, 0, 0, 0, 0, 0};
  if (part < 2)
    af = *(const s16x8*)(qT + ((size_t)b * N2 + (w * 16 + row16)) * NH_KD + h * 16 + part * 8);

  // --- QK^T: 13 K-frags direct from global, fully unrolled (compiler pipelines loads) ---
  const u16* kbase = kT + (size_t)b * NPOS * NH_KD + h * 16 + part * 8;
  f32x4 s[13];
#pragma unroll
  for (int f = 0; f < 13; f++) {
    s16x8 bf = (s16x8){0, 0, 0, 0, 0, 0, 0, 0};
    if (part < 2)
      bf = *(const s16x8*)(kbase + (size_t)(f * 16 + row16) * NH_KD);
    s[f] = __builtin_amdgcn_mfma_f32_16x16x32_bf16(af, bf, (f32x4){0.f, 0.f, 0.f, 0.f}, 0, 0, 0);
  }

  // --- V fragment geometry + iter-0 prefetch (hides under bias/softmax) ---
  const u16* vbase = v4 + ((size_t)b * DH + h * DHEAD) * NPOS;
  int vd = l & 15, vq8 = part * 8;
  auto VLOAD = [&](int f, int kk) {
    const u16* p = vbase + (size_t)(f * 16 + vd) * NPOS + kk + vq8;
    s16x8 r;
    ((u32x2*)&r)[0] = *(const u32x2*)(p);        // 8B-aligned
    ((u32x2*)&r)[1] = *(const u32x2*)(p + 4);
    return r;
  };
  s16x8 vb0[4];
#pragma unroll
  for (int f = 0; f < 4; f++) vb0[f] = VLOAD(f, 0);

  // --- scale + bias + mask, rolling 4-frag bias batches (16 VGPR live, not 64) ---
#pragma unroll
  for (int q = 0; q < 4; q++) {
    f32x4 bqr[4];
#pragma unroll
    for (int r = 0; r < 4; r++) {
      int mm = mbase + r; if (mm > N2 - 1) mm = N2 - 1;
      bqr[r] = *(const f32x4*)(bxp + (((size_t)h * N2 + mm) * 16 + ncol) * 16 + q * 4);
    }
#pragma unroll
    for (int ff = 0; ff < 4; ff++) {
      int f = q * 4 + ff;
      if (f < 13) {
        int n = f * 16 + ncol;
#pragma unroll
        for (int r = 0; r < 4; r++) {
          int m = mbase + r;
          s[f][r] = (m < N2 && n < NPOS) ? s[f][r] * SCALE_Q + bqr[r][ff] : -1e30f;
        }
      }
    }
  }
  // --- softmax: rows live in 16-lane groups -> shfl_xor 1,2,4,8 ---
#pragma unroll
  for (int r = 0; r < 4; r++) {
    float mx = s[0][r];
#pragma unroll
    for (int f = 1; f < 13; f++) mx = fmaxf(mx, s[f][r]);
    mx = fmaxf(mx, __shfl_xor(mx, 1)); mx = fmaxf(mx, __shfl_xor(mx, 2));
    mx = fmaxf(mx, __shfl_xor(mx, 4)); mx = fmaxf(mx, __shfl_xor(mx, 8));
    float sum = 0.f;
#pragma unroll
    for (int f = 0; f < 13; f++) { s[f][r] = __expf(s[f][r] - mx); sum += s[f][r]; }
    sum += __shfl_xor(sum, 1); sum += __shfl_xor(sum, 2);
    sum += __shfl_xor(sum, 4); sum += __shfl_xor(sum, 8);
    float inv = 1.f / sum;
#pragma unroll
    for (int f = 0; f < 13; f++) s[f][r] *= inv;
  }
  // --- P -> LDS (bf16), wave-local rows ---
#pragma unroll
  for (int f = 0; f < 13; f++) {
    int n = f * 16 + ncol;
#pragma unroll
    for (int r = 0; r < 4; r++)
      p_lds[(mbase + r) * 232 + n] = f2bf(s[f][r]);
  }
  __syncthreads();

  // --- PV: A = P rows (wave-local), B = V from global, 1-deep pipeline, K = 224 ---
  f32x4 o[4];
#pragma unroll
  for (int f = 0; f < 4; f++) o[f] = (f32x4){0.f, 0.f, 0.f, 0.f};
#pragma unroll
  for (int t = 0; t < 7; t++) {
    int kk = t * 32;
    s16x8 vn[4];
    if (t < 6) {
#pragma unroll
      for (int f = 0; f < 4; f++) vn[f] = VLOAD(f, kk + 32);
    }
    s16x8 pa = *(const s16x8*)(&p_lds[(w * 16 + row16) * 232 + kk + part * 8]);
#pragma unroll
    for (int f = 0; f < 4; f++)
      o[f] = __builtin_amdgcn_mfma_f32_16x16x32_bf16(pa, vb0[f], o[f], 0, 0, 0);
    if (t < 6) {
#pragma unroll
      for (int f = 0; f < 4; f++) vb0[f] = vn[f];
    }
  }
  __syncthreads();   // all waves done reading p_lds before o_lds overlays it

  // --- o -> o_lds ---
#pragma unroll
  for (int f = 0; f < 4; f++)
#pragma unroll
    for (int r = 0; r < 4; r++) {
      int m = mbase + r;
      if (m < N2) o_lds[m * 68 + f * 16 + ncol] = o[f][r];
    }
  __syncthreads();

  // --- cooperative epilogue: coalesced vlT add + gelu + gT store ---
  for (int idx = tid; idx < N2 * 16; idx += 256) {
    int row = idx >> 4, c4 = (idx & 15) << 2;
    f32x4 ov = *(const f32x4*)(&o_lds[row * 68 + c4]);
    size_t go = ((size_t)b * N2 + row) * DH + h * DHEAD + c4;
    s16x4 vv = *(const s16x4*)(vlT + go);
    s16x4 outv;
#pragma unroll
    for (int e = 0; e < 4; e++) {
      float xv = ov[e] + bf2f((u16)vv[e]);
      float g = 0.5f * xv * (1.f + erff(xv * 0.70710678118f));
      outv[e] = (short)f2bf(g);
    }
    *(s16x4*)(gT + go) = outv;
  }
}

extern "C" void kernel_launch(void* const* d_in, const int* in_sizes, int n_in,
                              void* d_out, int out_size, void* d_ws, size_t ws_size,
                              hipStream_t stream) {
  const float* x   = (const float*)d_in[0];
  const float* qlw = (const float*)d_in[1];
  const float* qlb = (const float*)d_in[2];
  const float* qpw = (const float*)d_in[3];
  const float* qpb = (const float*)d_in[4];
  const float* qbs = (const float*)d_in[5];
  const float* qbt = (const float*)d_in[6];
  const float* kw  = (const float*)d_in[7];
  const float* kb  = (const float*)d_in[8];
  const float* kbs = (const float*)d_in[9];
  const float* kbt = (const float*)d_in[10];
  const float* vw  = (const float*)d_in[11];
  const float* vb  = (const float*)d_in[12];
  const float* vbs = (const float*)d_in[13];
  const float* vbt = (const float*)d_in[14];
  const float* vlw = (const float*)d_in[15];
  const float* vlb = (const float*)d_in[16];
  const float* vls = (const float*)d_in[17];
  const float* vlt_in = (const float*)d_in[18];
  const float* pw  = (const float*)d_in[19];
  const float* pb  = (const float*)d_in[20];
  const float* pbs = (const float*)d_in[21];
  const float* pbt = (const float*)d_in[22];
  const float* ab  = (const float*)d_in[23];
  const int*   bidx = (const int*)d_in[24];
  int noff = in_sizes[23] / NUM_HEADS;

  char* ws = (char*)d_ws;
  size_t off = 0;
  auto alloc = [&](size_t bytes) { char* p = ws + off; off += (bytes + 255) & ~(size_t)255; return p; };
  u16* xbT = (u16*)alloc((size_t)BATCH * NPOS * DIM * 2);      // 77.1 MB (aliased by gT later)
  u16* kTm = (u16*)alloc((size_t)BATCH * NPOS * NH_KD * 2);    // 25.7 MB
  u16* qlT = (u16*)alloc((size_t)BATCH * N2 * DIM * 2);        // 19.3 MB
  u16* qTm = (u16*)alloc((size_t)BATCH * N2 * NH_KD * 2);      //  6.4 MB
  u16* v4m = (u16*)alloc((size_t)BATCH * DH * NPOS * 2);       // 102.8 MB
  u16* vlTm = (u16*)alloc((size_t)BATCH * N2 * DH * 2);        // 25.7 MB  (absorbs attn's OOB V reads)
  float* bxp = (float*)alloc((size_t)NUM_HEADS * N2 * 16 * 16 * 4);  // 0.8 MB
  u16* wb  = (u16*)alloc((size_t)640 * DIM * 2);               // concat [vw; kw]
  u16* qwb = (u16*)alloc((size_t)NH_KD * DIM * 2);
  u16* pwb = (u16*)alloc((size_t)OUT_DIM * DH * 2);
  float* cvb = (float*)alloc(640 * 4);
  float* cvs = (float*)alloc(640 * 4);
  float* cvt = (float*)alloc(640 * 4);
  u16* gTm = xbT;  // alias: all xbT readers complete before k_attn writes gT

  k_prep<<<(890752 + 255) / 256, 256, 0, stream>>>(kw, vw, qpw, pw, ab, bidx, noff,
                                                   kb, kbs, kbt, vb, vbs, vbt,
                                                   wb, qwb, pwb, bxp, cvb, cvs, cvt);

  k_transpose<<<dim3(6, BATCH), 256, 0, stream>>>(x, xbT);
  k_dwconv_q8<<<dim3((N2 * (DIM / 8) + 255) / 256, BATCH), 256, 0, stream>>>(xbT, qlw, qlb, qlT);

  // merged kv: A=wb[640][384] (m=ch; 0-511 v, 512-639 k), B=xbT (n=j); 5 m-tiles x 784 n-tiles
  k_gemm_flat<NPOS, false, true><<<3920, 256, 0, stream>>>(
      wb, xbT, v4m, kTm, cvb, cvs, cvt, DIM, 5, 0, (long)DH * NPOS);
  // q: A=qlT[25088][384] (m=j), B=qwb (n=ch) -> qTm[j][128]; 196 m-tiles x 1 n-tile
  k_gemm_flat<0, false, false><<<196, 256, 0, stream>>>(
      qlT, qwb, qTm, nullptr, qpb, qbs, qbt, DIM, 196, NH_KD, 0);

  k_dwconv_v<<<dim3(8, BATCH), 256, 0, stream>>>(v4m, vlw, vlb, vls, vlt_in, vlTm);
  k_attn_mfma<<<dim3(NUM_HEADS, BATCH), 256, 0, stream>>>(qTm, kTm, v4m, bxp, vlTm, gTm);

  // p: A=pwb[768][512] (m=ch), B=gTm[25088][512] (n=j) -> d_out[b][768][49] f32; 6 x 196
  k_gemm_flat<N2, true, false><<<1176, 256, 0, stream>>>(
      pwb, gTm, d_out, nullptr, pb, pbs, pbt, DH, 6, 0, (long)OUT_DIM * N2);
}